// Round 1
// baseline (981.660 us; speedup 1.0000x reference)
//
#include <hip/hip_runtime.h>
#include <stdint.h>

#define NE 8
#define NI 2816
#define NH 1024
#define NT 8192
#define NPAIR (NT * 2)

typedef __bf16 bf16x8 __attribute__((ext_vector_type(8)));
typedef float f32x4 __attribute__((ext_vector_type(4)));

__device__ __forceinline__ uint16_t f2bf(float f) {
    union { float f; uint32_t u; } v;
    v.f = f;
    return (uint16_t)((v.u + 0x7FFFu + ((v.u >> 16) & 1u)) >> 16);
}

// async global->LDS, 16B per lane. LDS dest must be lane-contiguous (wave-uniform
// base + lane*16). Generic->AS3 via 32-bit truncation (LDS aperture is 4GB-aligned).
__device__ __forceinline__ void gld16(const void* g, void* l) {
    __builtin_amdgcn_global_load_lds(
        (__attribute__((address_space(1))) void*)(uintptr_t)g,
        (__attribute__((address_space(3))) void*)(uint32_t)(uintptr_t)l,
        16, 0, 0);
}

// ---------------- fp32 -> bf16 weight conversion ----------------
__global__ __launch_bounds__(256) void k_cvt(const float* __restrict__ s,
                                             uint16_t* __restrict__ d, int n8) {
    int i = blockIdx.x * 256 + threadIdx.x;
    if (i >= n8) return;
    float4 a = ((const float4*)s)[(size_t)i * 2];
    float4 b = ((const float4*)s)[(size_t)i * 2 + 1];
    uint4 o;
    o.x = (uint32_t)f2bf(a.x) | ((uint32_t)f2bf(a.y) << 16);
    o.y = (uint32_t)f2bf(a.z) | ((uint32_t)f2bf(a.w) << 16);
    o.z = (uint32_t)f2bf(b.x) | ((uint32_t)f2bf(b.y) << 16);
    o.w = (uint32_t)f2bf(b.z) | ((uint32_t)f2bf(b.w) << 16);
    ((uint4*)d)[i] = o;
}

// ---------------- router: top-2 of softmax, renormalized ----------------
__global__ __launch_bounds__(256) void k_router(const float* __restrict__ logits,
                                                int* __restrict__ tok_e,
                                                float2* __restrict__ tok_w,
                                                int* __restrict__ counts) {
    int t = blockIdx.x * 256 + threadIdx.x;
    if (t >= NT) return;
    float4 a = ((const float4*)logits)[(size_t)t * 2];
    float4 b = ((const float4*)logits)[(size_t)t * 2 + 1];
    float l[8] = {a.x, a.y, a.z, a.w, b.x, b.y, b.z, b.w};
    int i0 = 0; float l0 = l[0];
#pragma unroll
    for (int e = 1; e < 8; e++) if (l[e] > l0) { l0 = l[e]; i0 = e; }
    int i1 = -1; float l1 = -3.4e38f;
#pragma unroll
    for (int e = 0; e < 8; e++) if (e != i0 && l[e] > l1) { l1 = l[e]; i1 = e; }
    // renormalized top-2 softmax == 2-way softmax of (l0, l1)
    float w0 = 1.f / (1.f + __expf(l1 - l0));
    float w1 = 1.f - w0;
    tok_e[t] = i0 | (i1 << 8);
    tok_w[t] = make_float2(w0, w1);
    atomicAdd(&counts[i0], 1);
    atomicAdd(&counts[i1], 1);
}

__global__ void k_scan(const int* __restrict__ counts, int* __restrict__ offsets,
                       int* __restrict__ cursor) {
    if (threadIdx.x == 0) {
        int o = 0;
        for (int e = 0; e < NE; e++) { offsets[e] = o; cursor[e] = o; o += counts[e]; }
    }
}

// ---------------- gather routed x rows into per-expert bf16 panels ----------------
__global__ __launch_bounds__(128) void k_gather(const float* __restrict__ x,
                                                const int* __restrict__ tok_e,
                                                const float2* __restrict__ tok_w,
                                                int* __restrict__ cursor,
                                                uint16_t* __restrict__ Xg,
                                                int* __restrict__ slot_tok,
                                                float* __restrict__ slot_w) {
    int t = blockIdx.x;
    __shared__ int ss[2];
    if (threadIdx.x == 0) {
        int ee = tok_e[t];
        float2 w = tok_w[t];
        int s0 = atomicAdd(&cursor[ee & 0xff], 1);
        int s1 = atomicAdd(&cursor[(ee >> 8) & 0xff], 1);
        ss[0] = s0; ss[1] = s1;
        slot_tok[s0] = t; slot_w[s0] = w.x;
        slot_tok[s1] = t; slot_w[s1] = w.y;
    }
    __syncthreads();
    int s0 = ss[0], s1 = ss[1];
    int i = threadIdx.x;  // 8 floats each
    const float4* xr = (const float4*)(x + (size_t)t * NH);
    float4 a = xr[i * 2];
    float4 b = xr[i * 2 + 1];
    uint4 o;
    o.x = (uint32_t)f2bf(a.x) | ((uint32_t)f2bf(a.y) << 16);
    o.y = (uint32_t)f2bf(a.z) | ((uint32_t)f2bf(a.w) << 16);
    o.z = (uint32_t)f2bf(b.x) | ((uint32_t)f2bf(b.y) << 16);
    o.w = (uint32_t)f2bf(b.z) | ((uint32_t)f2bf(b.w) << 16);
    ((uint4*)(Xg + (size_t)s0 * NH))[i] = o;
    ((uint4*)(Xg + (size_t)s1 * NH))[i] = o;
}

// ---------------- G1: Hbuf = silu(X@W1^T) * (X@W3^T), per expert ----------------
__global__ __launch_bounds__(256, 2) void k_gemm1(const uint16_t* __restrict__ Xg,
                                                  const uint16_t* __restrict__ W1b,
                                                  const uint16_t* __restrict__ W3b,
                                                  uint16_t* __restrict__ Hbuf,
                                                  const int* __restrict__ counts,
                                                  const int* __restrict__ offsets) {
    int e = blockIdx.z;
    int n_e = counts[e];
    int mtile = blockIdx.y;
    if (mtile * 128 >= n_e) return;
    int ntile = blockIdx.x;
    int off = offsets[e];

    __shared__ __align__(16) uint16_t As[128 * 32];
    __shared__ __align__(16) uint16_t B1s[128 * 32];
    __shared__ __align__(16) uint16_t B3s[128 * 32];

    int tid = threadIdx.x;
    int r = tid >> 2, c = tid & 3;
    int wv = tid >> 6, lane = tid & 63;
    int wr = wv >> 1, wc = wv & 1;
    int m_in = lane & 15, q = lane >> 4;

    // staging source rows (A rows clamped to buffer end to avoid OOB on tail tiles)
    int rowA0 = off + mtile * 128 + r;
    int rowA1 = min(rowA0 + 64, NPAIR - 1);
    rowA0 = min(rowA0, NPAIR - 1);
    const uint16_t* a0 = Xg + (size_t)rowA0 * NH + c * 8;
    const uint16_t* a1 = Xg + (size_t)rowA1 * NH + c * 8;
    const uint16_t* b1r = W1b + ((size_t)e * NI + ntile * 128 + r) * NH + c * 8;
    const uint16_t* b3r = W3b + ((size_t)e * NI + ntile * 128 + r) * NH + c * 8;

    uint16_t* lA0 = &As[tid * 8];   uint16_t* lA1 = &As[2048 + tid * 8];
    uint16_t* lB10 = &B1s[tid * 8]; uint16_t* lB11 = &B1s[2048 + tid * 8];
    uint16_t* lB30 = &B3s[tid * 8]; uint16_t* lB31 = &B3s[2048 + tid * 8];

    const uint16_t* pa = &As[(wr * 64 + m_in) * 32 + q * 8];
    const uint16_t* pb1 = &B1s[(wc * 64 + m_in) * 32 + q * 8];
    const uint16_t* pb3 = &B3s[(wc * 64 + m_in) * 32 + q * 8];

    f32x4 acc1[4][4] = {};
    f32x4 acc3[4][4] = {};

    for (int k0 = 0; k0 < NH; k0 += 32) {
        gld16(a0 + k0, lA0);
        gld16(a1 + k0, lA1);
        gld16(b1r + k0, lB10);
        gld16(b1r + (size_t)64 * NH + k0, lB11);
        gld16(b3r + k0, lB30);
        gld16(b3r + (size_t)64 * NH + k0, lB31);
        __syncthreads();

        bf16x8 af[4], b1f[4], b3f[4];
#pragma unroll
        for (int it = 0; it < 4; it++) af[it] = *(const bf16x8*)(pa + it * 512);
#pragma unroll
        for (int jt = 0; jt < 4; jt++) {
            b1f[jt] = *(const bf16x8*)(pb1 + jt * 512);
            b3f[jt] = *(const bf16x8*)(pb3 + jt * 512);
        }
#pragma unroll
        for (int it = 0; it < 4; it++)
#pragma unroll
            for (int jt = 0; jt < 4; jt++) {
                acc1[it][jt] = __builtin_amdgcn_mfma_f32_16x16x32_bf16(af[it], b1f[jt], acc1[it][jt], 0, 0, 0);
                acc3[it][jt] = __builtin_amdgcn_mfma_f32_16x16x32_bf16(af[it], b3f[jt], acc3[it][jt], 0, 0, 0);
            }
        __syncthreads();
    }

    int sBase = off + mtile * 128;
#pragma unroll
    for (int it = 0; it < 4; it++) {
#pragma unroll
        for (int reg = 0; reg < 4; reg++) {
            int lm = wr * 64 + it * 16 + q * 4 + reg;
            if (mtile * 128 + lm < n_e) {
                uint16_t* orow = Hbuf + (size_t)(sBase + lm) * NI + ntile * 128 + wc * 64 + m_in;
#pragma unroll
                for (int jt = 0; jt < 4; jt++) {
                    float c1 = acc1[it][jt][reg];
                    float c3 = acc3[it][jt][reg];
                    float hv = (c1 / (1.f + __expf(-c1))) * c3;  // silu(c1)*c3
                    orow[jt * 16] = f2bf(hv);
                }
            }
        }
    }
}

// ---------------- G2: out[tok] += w * (H @ W2^T), per expert ----------------
__global__ __launch_bounds__(256, 2) void k_gemm2(const uint16_t* __restrict__ Hbuf,
                                                  const uint16_t* __restrict__ W2b,
                                                  float* __restrict__ out,
                                                  const int* __restrict__ counts,
                                                  const int* __restrict__ offsets,
                                                  const int* __restrict__ slot_tok,
                                                  const float* __restrict__ slot_w) {
    int e = blockIdx.z;
    int n_e = counts[e];
    int mtile = blockIdx.y;
    if (mtile * 128 >= n_e) return;
    int ntile = blockIdx.x;  // 0..7
    int off = offsets[e];

    __shared__ __align__(16) uint16_t As[128 * 32];
    __shared__ __align__(16) uint16_t Bs[128 * 32];

    int tid = threadIdx.x;
    int r = tid >> 2, c = tid & 3;
    int wv = tid >> 6, lane = tid & 63;
    int wr = wv >> 1, wc = wv & 1;
    int m_in = lane & 15, q = lane >> 4;

    int rowA0 = off + mtile * 128 + r;
    int rowA1 = min(rowA0 + 64, NPAIR - 1);
    rowA0 = min(rowA0, NPAIR - 1);
    const uint16_t* a0 = Hbuf + (size_t)rowA0 * NI + c * 8;
    const uint16_t* a1 = Hbuf + (size_t)rowA1 * NI + c * 8;
    const uint16_t* br = W2b + ((size_t)e * NH + ntile * 128 + r) * NI + c * 8;

    uint16_t* lA0 = &As[tid * 8]; uint16_t* lA1 = &As[2048 + tid * 8];
    uint16_t* lB0 = &Bs[tid * 8]; uint16_t* lB1 = &Bs[2048 + tid * 8];

    const uint16_t* pa = &As[(wr * 64 + m_in) * 32 + q * 8];
    const uint16_t* pb = &Bs[(wc * 64 + m_in) * 32 + q * 8];

    f32x4 acc[4][4] = {};

    for (int k0 = 0; k0 < NI; k0 += 32) {
        gld16(a0 + k0, lA0);
        gld16(a1 + k0, lA1);
        gld16(br + k0, lB0);
        gld16(br + (size_t)64 * NI + k0, lB1);
        __syncthreads();

        bf16x8 af[4], bf[4];
#pragma unroll
        for (int it = 0; it < 4; it++) af[it] = *(const bf16x8*)(pa + it * 512);
#pragma unroll
        for (int jt = 0; jt < 4; jt++) bf[jt] = *(const bf16x8*)(pb + jt * 512);
#pragma unroll
        for (int it = 0; it < 4; it++)
#pragma unroll
            for (int jt = 0; jt < 4; jt++)
                acc[it][jt] = __builtin_amdgcn_mfma_f32_16x16x32_bf16(af[it], bf[jt], acc[it][jt], 0, 0, 0);
        __syncthreads();
    }

    int sBase = off + mtile * 128;
#pragma unroll
    for (int it = 0; it < 4; it++) {
#pragma unroll
        for (int reg = 0; reg < 4; reg++) {
            int lm = wr * 64 + it * 16 + q * 4 + reg;
            if (mtile * 128 + lm < n_e) {
                int slot = sBase + lm;
                int tk = slot_tok[slot];
                float w = slot_w[slot];
                float* orow = out + (size_t)tk * NH + ntile * 128 + wc * 64 + m_in;
#pragma unroll
                for (int jt = 0; jt < 4; jt++) {
#if defined(__HIP_DEVICE_COMPILE__)
                    unsafeAtomicAdd(&orow[jt * 16], acc[it][jt][reg] * w);
#else
                    atomicAdd(&orow[jt * 16], acc[it][jt][reg] * w);
#endif
                }
            }
        }
    }
}

extern "C" void kernel_launch(void* const* d_in, const int* in_sizes, int n_in,
                              void* d_out, int out_size, void* d_ws, size_t ws_size,
                              hipStream_t stream) {
    const float* x = (const float*)d_in[0];
    const float* logits = (const float*)d_in[1];
    const float* W1 = (const float*)d_in[2];
    const float* W3 = (const float*)d_in[3];
    const float* W2 = (const float*)d_in[4];
    float* out = (float*)d_out;

    char* ws = (char*)d_ws;
    size_t o = 0;
    auto nxt = [&](size_t b) -> void* {
        void* p = ws + o;
        o += (b + 255) & ~(size_t)255;
        return p;
    };
    const size_t WELEMS = (size_t)NE * NI * NH;  // 23,068,672 (same for W1/W3/W2)
    uint16_t* W1b = (uint16_t*)nxt(WELEMS * 2);
    uint16_t* W3b = (uint16_t*)nxt(WELEMS * 2);
    uint16_t* W2b = (uint16_t*)nxt(WELEMS * 2);
    uint16_t* Xg = (uint16_t*)nxt((size_t)NPAIR * NH * 2);
    uint16_t* Hbuf = (uint16_t*)nxt((size_t)NPAIR * NI * 2);
    int* slot_tok = (int*)nxt((size_t)NPAIR * 4);
    float* slot_w = (float*)nxt((size_t)NPAIR * 4);
    int* tok_e = (int*)nxt((size_t)NT * 4);
    float2* tok_w = (float2*)nxt((size_t)NT * 8);
    int* meta = (int*)nxt(128);  // counts[8] | offsets[8] | cursor[8]
    int* counts = meta;
    int* offsets = meta + 8;
    int* cursor = meta + 16;
    (void)ws_size; (void)in_sizes; (void)n_in;

    hipMemsetAsync(meta, 0, 128, stream);
    hipMemsetAsync(d_out, 0, (size_t)out_size * sizeof(float), stream);

    k_router<<<NT / 256, 256, 0, stream>>>(logits, tok_e, tok_w, counts);
    k_scan<<<1, 64, 0, stream>>>(counts, offsets, cursor);

    int n8 = (int)(WELEMS / 8);  // 2,883,584 -> 11264 blocks
    k_cvt<<<n8 / 256, 256, 0, stream>>>(W1, W1b, n8);
    k_cvt<<<n8 / 256, 256, 0, stream>>>(W3, W3b, n8);
    k_cvt<<<n8 / 256, 256, 0, stream>>>(W2, W2b, n8);

    k_gather<<<NT, 128, 0, stream>>>(x, tok_e, tok_w, cursor, Xg, slot_tok, slot_w);

    k_gemm1<<<dim3(NI / 128, NT / 128, NE), 256, 0, stream>>>(Xg, W1b, W3b, Hbuf, counts, offsets);
    k_gemm2<<<dim3(NH / 128, NT / 128, NE), 256, 0, stream>>>(Hbuf, W2b, out, counts, offsets, slot_tok, slot_w);
}

// Round 2
// 961.048 us; speedup vs baseline: 1.0214x; 1.0214x over previous
//
#include <hip/hip_runtime.h>
#include <stdint.h>

#define NE 8
#define NI 2816
#define NH 1024
#define NT 8192
#define NPAIR (NT * 2)

typedef __bf16 bf16x8 __attribute__((ext_vector_type(8)));
typedef float f32x4 __attribute__((ext_vector_type(4)));

__device__ __forceinline__ uint16_t f2bf(float f) {
    union { float f; uint32_t u; } v;
    v.f = f;
    return (uint16_t)((v.u + 0x7FFFu + ((v.u >> 16) & 1u)) >> 16);
}

__device__ __forceinline__ float bflo(uint32_t u) {
    union { uint32_t x; float f; } v; v.x = u << 16; return v.f;
}
__device__ __forceinline__ float bfhi(uint32_t u) {
    union { uint32_t x; float f; } v; v.x = u & 0xffff0000u; return v.f;
}

// async global->LDS, 16B per lane. LDS dest must be lane-contiguous (wave-uniform
// base + lane*16). Generic->AS3 via 32-bit truncation (LDS aperture is 4GB-aligned).
__device__ __forceinline__ void gld16(const void* g, void* l) {
    __builtin_amdgcn_global_load_lds(
        (__attribute__((address_space(1))) void*)(uintptr_t)g,
        (__attribute__((address_space(3))) void*)(uint32_t)(uintptr_t)l,
        16, 0, 0);
}

// ---------------- fp32 -> bf16 weight conversion (all 3 weights, one launch) ----
__global__ __launch_bounds__(256) void k_cvt3(const float* __restrict__ W1,
                                              const float* __restrict__ W3,
                                              const float* __restrict__ W2,
                                              uint16_t* __restrict__ W1b,
                                              uint16_t* __restrict__ W3b,
                                              uint16_t* __restrict__ W2b) {
    int i = blockIdx.x * 256 + threadIdx.x;  // [0, WELEMS/8)
    const float* s = blockIdx.y == 0 ? W1 : (blockIdx.y == 1 ? W3 : W2);
    uint16_t* d = blockIdx.y == 0 ? W1b : (blockIdx.y == 1 ? W3b : W2b);
    float4 a = ((const float4*)s)[(size_t)i * 2];
    float4 b = ((const float4*)s)[(size_t)i * 2 + 1];
    uint4 o;
    o.x = (uint32_t)f2bf(a.x) | ((uint32_t)f2bf(a.y) << 16);
    o.y = (uint32_t)f2bf(a.z) | ((uint32_t)f2bf(a.w) << 16);
    o.z = (uint32_t)f2bf(b.x) | ((uint32_t)f2bf(b.y) << 16);
    o.w = (uint32_t)f2bf(b.z) | ((uint32_t)f2bf(b.w) << 16);
    ((uint4*)d)[i] = o;
}

// ---------------- router: top-2 of softmax, renormalized ----------------
__global__ __launch_bounds__(256) void k_router(const float* __restrict__ logits,
                                                int* __restrict__ tok_e,
                                                float2* __restrict__ tok_w,
                                                int* __restrict__ counts) {
    int t = blockIdx.x * 256 + threadIdx.x;
    if (t >= NT) return;
    float4 a = ((const float4*)logits)[(size_t)t * 2];
    float4 b = ((const float4*)logits)[(size_t)t * 2 + 1];
    float l[8] = {a.x, a.y, a.z, a.w, b.x, b.y, b.z, b.w};
    int i0 = 0; float l0 = l[0];
#pragma unroll
    for (int e = 1; e < 8; e++) if (l[e] > l0) { l0 = l[e]; i0 = e; }
    int i1 = -1; float l1 = -3.4e38f;
#pragma unroll
    for (int e = 0; e < 8; e++) if (e != i0 && l[e] > l1) { l1 = l[e]; i1 = e; }
    // renormalized top-2 softmax == 2-way softmax of (l0, l1)
    float w0 = 1.f / (1.f + __expf(l1 - l0));
    float w1 = 1.f - w0;
    tok_e[t] = i0 | (i1 << 8);
    tok_w[t] = make_float2(w0, w1);
    atomicAdd(&counts[i0], 1);
    atomicAdd(&counts[i1], 1);
}

__global__ void k_scan(const int* __restrict__ counts, int* __restrict__ offsets,
                       int* __restrict__ cursor) {
    if (threadIdx.x == 0) {
        int o = 0;
        for (int e = 0; e < NE; e++) { offsets[e] = o; cursor[e] = o; o += counts[e]; }
    }
}

// ---------------- gather routed x rows into per-expert bf16 panels ----------------
__global__ __launch_bounds__(128) void k_gather(const float* __restrict__ x,
                                                const int* __restrict__ tok_e,
                                                const float2* __restrict__ tok_w,
                                                int* __restrict__ cursor,
                                                uint16_t* __restrict__ Xg,
                                                int2* __restrict__ tok_slots,
                                                float* __restrict__ slot_w) {
    int t = blockIdx.x;
    __shared__ int ss[2];
    if (threadIdx.x == 0) {
        int ee = tok_e[t];
        float2 w = tok_w[t];
        int s0 = atomicAdd(&cursor[ee & 0xff], 1);
        int s1 = atomicAdd(&cursor[(ee >> 8) & 0xff], 1);
        ss[0] = s0; ss[1] = s1;
        tok_slots[t] = make_int2(s0, s1);
        slot_w[s0] = w.x;
        slot_w[s1] = w.y;
    }
    __syncthreads();
    int s0 = ss[0], s1 = ss[1];
    int i = threadIdx.x;  // 8 floats each
    const float4* xr = (const float4*)(x + (size_t)t * NH);
    float4 a = xr[i * 2];
    float4 b = xr[i * 2 + 1];
    uint4 o;
    o.x = (uint32_t)f2bf(a.x) | ((uint32_t)f2bf(a.y) << 16);
    o.y = (uint32_t)f2bf(a.z) | ((uint32_t)f2bf(a.w) << 16);
    o.z = (uint32_t)f2bf(b.x) | ((uint32_t)f2bf(b.y) << 16);
    o.w = (uint32_t)f2bf(b.z) | ((uint32_t)f2bf(b.w) << 16);
    ((uint4*)(Xg + (size_t)s0 * NH))[i] = o;
    ((uint4*)(Xg + (size_t)s1 * NH))[i] = o;
}

// ---------------- G1: Hbuf = silu(X@W1^T) * (X@W3^T), per expert ----------------
__global__ __launch_bounds__(256, 2) void k_gemm1(const uint16_t* __restrict__ Xg,
                                                  const uint16_t* __restrict__ W1b,
                                                  const uint16_t* __restrict__ W3b,
                                                  uint16_t* __restrict__ Hbuf,
                                                  const int* __restrict__ counts,
                                                  const int* __restrict__ offsets) {
    int e = blockIdx.z;
    int n_e = counts[e];
    int mtile = blockIdx.y;
    if (mtile * 128 >= n_e) return;
    int ntile = blockIdx.x;
    int off = offsets[e];

    __shared__ __align__(16) uint16_t As[128 * 32];
    __shared__ __align__(16) uint16_t B1s[128 * 32];
    __shared__ __align__(16) uint16_t B3s[128 * 32];

    int tid = threadIdx.x;
    int r = tid >> 2, c = tid & 3;
    int wv = tid >> 6, lane = tid & 63;
    int wr = wv >> 1, wc = wv & 1;
    int m_in = lane & 15, q = lane >> 4;

    // staging source rows (A rows clamped to buffer end to avoid OOB on tail tiles)
    int rowA0 = off + mtile * 128 + r;
    int rowA1 = min(rowA0 + 64, NPAIR - 1);
    rowA0 = min(rowA0, NPAIR - 1);
    const uint16_t* a0 = Xg + (size_t)rowA0 * NH + c * 8;
    const uint16_t* a1 = Xg + (size_t)rowA1 * NH + c * 8;
    const uint16_t* b1r = W1b + ((size_t)e * NI + ntile * 128 + r) * NH + c * 8;
    const uint16_t* b3r = W3b + ((size_t)e * NI + ntile * 128 + r) * NH + c * 8;

    uint16_t* lA0 = &As[tid * 8];   uint16_t* lA1 = &As[2048 + tid * 8];
    uint16_t* lB10 = &B1s[tid * 8]; uint16_t* lB11 = &B1s[2048 + tid * 8];
    uint16_t* lB30 = &B3s[tid * 8]; uint16_t* lB31 = &B3s[2048 + tid * 8];

    const uint16_t* pa = &As[(wr * 64 + m_in) * 32 + q * 8];
    const uint16_t* pb1 = &B1s[(wc * 64 + m_in) * 32 + q * 8];
    const uint16_t* pb3 = &B3s[(wc * 64 + m_in) * 32 + q * 8];

    f32x4 acc1[4][4] = {};
    f32x4 acc3[4][4] = {};

    for (int k0 = 0; k0 < NH; k0 += 32) {
        gld16(a0 + k0, lA0);
        gld16(a1 + k0, lA1);
        gld16(b1r + k0, lB10);
        gld16(b1r + (size_t)64 * NH + k0, lB11);
        gld16(b3r + k0, lB30);
        gld16(b3r + (size_t)64 * NH + k0, lB31);
        __syncthreads();

        bf16x8 af[4], b1f[4], b3f[4];
#pragma unroll
        for (int it = 0; it < 4; it++) af[it] = *(const bf16x8*)(pa + it * 512);
#pragma unroll
        for (int jt = 0; jt < 4; jt++) {
            b1f[jt] = *(const bf16x8*)(pb1 + jt * 512);
            b3f[jt] = *(const bf16x8*)(pb3 + jt * 512);
        }
#pragma unroll
        for (int it = 0; it < 4; it++)
#pragma unroll
            for (int jt = 0; jt < 4; jt++) {
                acc1[it][jt] = __builtin_amdgcn_mfma_f32_16x16x32_bf16(af[it], b1f[jt], acc1[it][jt], 0, 0, 0);
                acc3[it][jt] = __builtin_amdgcn_mfma_f32_16x16x32_bf16(af[it], b3f[jt], acc3[it][jt], 0, 0, 0);
            }
        __syncthreads();
    }

    int sBase = off + mtile * 128;
#pragma unroll
    for (int it = 0; it < 4; it++) {
#pragma unroll
        for (int reg = 0; reg < 4; reg++) {
            int lm = wr * 64 + it * 16 + q * 4 + reg;
            if (mtile * 128 + lm < n_e) {
                uint16_t* orow = Hbuf + (size_t)(sBase + lm) * NI + ntile * 128 + wc * 64 + m_in;
#pragma unroll
                for (int jt = 0; jt < 4; jt++) {
                    float c1 = acc1[it][jt][reg];
                    float c3 = acc3[it][jt][reg];
                    float hv = (c1 / (1.f + __expf(-c1))) * c3;  // silu(c1)*c3
                    orow[jt * 16] = f2bf(hv);
                }
            }
        }
    }
}

// ---------------- G2: Ybuf[slot] = H @ W2^T (unweighted, plain bf16 stores) ------
__global__ __launch_bounds__(256, 2) void k_gemm2(const uint16_t* __restrict__ Hbuf,
                                                  const uint16_t* __restrict__ W2b,
                                                  uint16_t* __restrict__ Ybuf,
                                                  const int* __restrict__ counts,
                                                  const int* __restrict__ offsets) {
    int e = blockIdx.z;
    int n_e = counts[e];
    int mtile = blockIdx.y;
    if (mtile * 128 >= n_e) return;
    int ntile = blockIdx.x;  // 0..7
    int off = offsets[e];

    __shared__ __align__(16) uint16_t As[128 * 32];
    __shared__ __align__(16) uint16_t Bs[128 * 32];

    int tid = threadIdx.x;
    int r = tid >> 2, c = tid & 3;
    int wv = tid >> 6, lane = tid & 63;
    int wr = wv >> 1, wc = wv & 1;
    int m_in = lane & 15, q = lane >> 4;

    int rowA0 = off + mtile * 128 + r;
    int rowA1 = min(rowA0 + 64, NPAIR - 1);
    rowA0 = min(rowA0, NPAIR - 1);
    const uint16_t* a0 = Hbuf + (size_t)rowA0 * NI + c * 8;
    const uint16_t* a1 = Hbuf + (size_t)rowA1 * NI + c * 8;
    const uint16_t* br = W2b + ((size_t)e * NH + ntile * 128 + r) * NI + c * 8;

    uint16_t* lA0 = &As[tid * 8]; uint16_t* lA1 = &As[2048 + tid * 8];
    uint16_t* lB0 = &Bs[tid * 8]; uint16_t* lB1 = &Bs[2048 + tid * 8];

    const uint16_t* pa = &As[(wr * 64 + m_in) * 32 + q * 8];
    const uint16_t* pb = &Bs[(wc * 64 + m_in) * 32 + q * 8];

    f32x4 acc[4][4] = {};

    for (int k0 = 0; k0 < NI; k0 += 32) {
        gld16(a0 + k0, lA0);
        gld16(a1 + k0, lA1);
        gld16(br + k0, lB0);
        gld16(br + (size_t)64 * NI + k0, lB1);
        __syncthreads();

        bf16x8 af[4], bf[4];
#pragma unroll
        for (int it = 0; it < 4; it++) af[it] = *(const bf16x8*)(pa + it * 512);
#pragma unroll
        for (int jt = 0; jt < 4; jt++) bf[jt] = *(const bf16x8*)(pb + jt * 512);
#pragma unroll
        for (int it = 0; it < 4; it++)
#pragma unroll
            for (int jt = 0; jt < 4; jt++)
                acc[it][jt] = __builtin_amdgcn_mfma_f32_16x16x32_bf16(af[it], bf[jt], acc[it][jt], 0, 0, 0);
        __syncthreads();
    }

    int sBase = off + mtile * 128;
#pragma unroll
    for (int it = 0; it < 4; it++) {
#pragma unroll
        for (int reg = 0; reg < 4; reg++) {
            int lm = wr * 64 + it * 16 + q * 4 + reg;
            if (mtile * 128 + lm < n_e) {
                uint16_t* orow = Ybuf + (size_t)(sBase + lm) * NH + ntile * 128 + wc * 64 + m_in;
#pragma unroll
                for (int jt = 0; jt < 4; jt++)
                    orow[jt * 16] = f2bf(acc[it][jt][reg]);
            }
        }
    }
}

// ---------------- combine: out[t] = w0*Y[s0] + w1*Y[s1] (fp32) ----------------
__global__ __launch_bounds__(256) void k_combine(const uint16_t* __restrict__ Y,
                                                 const int2* __restrict__ tok_slots,
                                                 const float* __restrict__ slot_w,
                                                 float* __restrict__ out) {
    int idx = blockIdx.x * 256 + threadIdx.x;  // NT*NH/8 threads
    int t = idx >> 7;       // NH/8 = 128 groups per token
    int g = idx & 127;
    int2 s = tok_slots[t];
    float w0 = slot_w[s.x], w1 = slot_w[s.y];
    uint4 u0 = ((const uint4*)(Y + (size_t)s.x * NH))[g];
    uint4 u1 = ((const uint4*)(Y + (size_t)s.y * NH))[g];
    float4 o0, o1;
    o0.x = w0 * bflo(u0.x) + w1 * bflo(u1.x);
    o0.y = w0 * bfhi(u0.x) + w1 * bfhi(u1.x);
    o0.z = w0 * bflo(u0.y) + w1 * bflo(u1.y);
    o0.w = w0 * bfhi(u0.y) + w1 * bfhi(u1.y);
    o1.x = w0 * bflo(u0.z) + w1 * bflo(u1.z);
    o1.y = w0 * bfhi(u0.z) + w1 * bfhi(u1.z);
    o1.z = w0 * bflo(u0.w) + w1 * bflo(u1.w);
    o1.w = w0 * bfhi(u0.w) + w1 * bfhi(u1.w);
    float4* orow = (float4*)(out + (size_t)t * NH + g * 8);
    orow[0] = o0;
    orow[1] = o1;
}

extern "C" void kernel_launch(void* const* d_in, const int* in_sizes, int n_in,
                              void* d_out, int out_size, void* d_ws, size_t ws_size,
                              hipStream_t stream) {
    const float* x = (const float*)d_in[0];
    const float* logits = (const float*)d_in[1];
    const float* W1 = (const float*)d_in[2];
    const float* W3 = (const float*)d_in[3];
    const float* W2 = (const float*)d_in[4];
    float* out = (float*)d_out;

    char* ws = (char*)d_ws;
    size_t o = 0;
    auto nxt = [&](size_t b) -> void* {
        void* p = ws + o;
        o += (b + 255) & ~(size_t)255;
        return p;
    };
    const size_t WELEMS = (size_t)NE * NI * NH;  // 23,068,672 per weight
    uint16_t* W1b = (uint16_t*)nxt(WELEMS * 2);
    uint16_t* W3b = (uint16_t*)nxt(WELEMS * 2);
    uint16_t* W2b = (uint16_t*)nxt(WELEMS * 2);
    uint16_t* Xg = (uint16_t*)nxt((size_t)NPAIR * NH * 2);  // aliased as Ybuf after gemm1
    uint16_t* Hbuf = (uint16_t*)nxt((size_t)NPAIR * NI * 2);
    float* slot_w = (float*)nxt((size_t)NPAIR * 4);
    int2* tok_slots = (int2*)nxt((size_t)NT * 8);
    int* tok_e = (int*)nxt((size_t)NT * 4);
    float2* tok_w = (float2*)nxt((size_t)NT * 8);
    int* meta = (int*)nxt(128);  // counts[8] | offsets[8] | cursor[8]
    int* counts = meta;
    int* offsets = meta + 8;
    int* cursor = meta + 16;
    uint16_t* Ybuf = Xg;  // Xg is dead after gemm1; same size (NPAIR*NH*2B)
    (void)ws_size; (void)in_sizes; (void)n_in;

    hipMemsetAsync(meta, 0, 128, stream);

    k_router<<<NT / 256, 256, 0, stream>>>(logits, tok_e, tok_w, counts);
    k_scan<<<1, 64, 0, stream>>>(counts, offsets, cursor);

    k_cvt3<<<dim3((unsigned)(WELEMS / 8 / 256), 3), 256, 0, stream>>>(W1, W3, W2, W1b, W3b, W2b);

    k_gather<<<NT, 128, 0, stream>>>(x, tok_e, tok_w, cursor, Xg, tok_slots, slot_w);

    k_gemm1<<<dim3(NI / 128, NT / 128, NE), 256, 0, stream>>>(Xg, W1b, W3b, Hbuf, counts, offsets);
    k_gemm2<<<dim3(NH / 128, NT / 128, NE), 256, 0, stream>>>(Hbuf, W2b, Ybuf, counts, offsets);
    k_combine<<<NT * NH / 8 / 256, 256, 0, stream>>>(Ybuf, tok_slots, slot_w, out);
}